// Round 1
// baseline (684.111 us; speedup 1.0000x reference)
//
#include <hip/hip_runtime.h>

typedef unsigned short u16;
typedef short bf16x8 __attribute__((ext_vector_type(8)));
typedef float f32x4 __attribute__((ext_vector_type(4)));

#define GLB __attribute__((address_space(1)))
#define LDSAS __attribute__((address_space(3)))

constexpr int S = 2048, D = 4096, NH = 32, NHK = 8, DHD = 128;

__device__ __forceinline__ u16 f2b(float f) {
    union { float f; unsigned u; } v; v.f = f;
    return (u16)((v.u + 0x7fffu + ((v.u >> 16) & 1u)) >> 16);
}
__device__ __forceinline__ float b2f(u16 b) {
    union { unsigned u; float f; } v; v.u = ((unsigned)b) << 16;
    return v.f;
}
__device__ __forceinline__ void gload16(const void* g, void* l) {
    __builtin_amdgcn_global_load_lds((const GLB unsigned int*)g,
                                     (LDSAS unsigned int*)l, 16, 0, 0);
}

// ---------------- f32 -> bf16 elementwise (8/thread) ----------------
__global__ __launch_bounds__(256) void cvt_x(const float* __restrict__ in,
                                             u16* __restrict__ out, int n8) {
    int i = blockIdx.x * 256 + threadIdx.x;
    if (i >= n8) return;
    const float4* p = (const float4*)in + (size_t)i * 2;
    float4 a = p[0], b = p[1];
    uint4 o;
    o.x = f2b(a.x) | ((unsigned)f2b(a.y) << 16);
    o.y = f2b(a.z) | ((unsigned)f2b(a.w) << 16);
    o.z = f2b(b.x) | ((unsigned)f2b(b.y) << 16);
    o.w = f2b(b.z) | ((unsigned)f2b(b.w) << 16);
    *(uint4*)(out + (size_t)i * 8) = o;
}

// ---------------- f32 [R][C] -> bf16 [C][R] ----------------
__global__ __launch_bounds__(256) void tconv(const float* __restrict__ in,
                                             u16* __restrict__ out, int R, int C) {
    __shared__ float t[64][65];
    int r0 = blockIdx.y * 64, c0 = blockIdx.x * 64;
    int tx = threadIdx.x & 63, ty = threadIdx.x >> 6;
#pragma unroll
    for (int i = 0; i < 64; i += 4)
        t[ty + i][tx] = in[(size_t)(r0 + ty + i) * C + c0 + tx];
    __syncthreads();
#pragma unroll
    for (int i = 0; i < 64; i += 4)
        out[(size_t)(c0 + ty + i) * R + r0 + tx] = f2b(t[tx][ty + i]);
}

// ---------------- bf16 V [s][1024] -> Vt [h][d][s] ----------------
__global__ __launch_bounds__(256) void vtrans(const u16* __restrict__ V,
                                              u16* __restrict__ Vt) {
    __shared__ u16 t[64][65];
    int h = blockIdx.z;
    int s0 = blockIdx.x * 64, d0 = blockIdx.y * 64;
    int tx = threadIdx.x & 63, ty = threadIdx.x >> 6;
#pragma unroll
    for (int i = 0; i < 64; i += 4)
        t[ty + i][tx] = V[(size_t)(s0 + ty + i) * 1024 + h * 128 + d0 + tx];
    __syncthreads();
#pragma unroll
    for (int i = 0; i < 64; i += 4)
        Vt[(size_t)h * 128 * 2048 + (size_t)(d0 + ty + i) * 2048 + s0 + tx] = t[tx][ty + i];
}

// ---------------- RoPE in place on bf16 [s][nh*128] ----------------
template <int NHEADS>
__global__ __launch_bounds__(256) void rope_k(u16* __restrict__ T,
                                              const int* __restrict__ pos) {
    int idx = blockIdx.x * 256 + threadIdx.x;
    int d = idx & 63;
    int h = (idx >> 6) & (NHEADS - 1);
    int s = idx >> (6 + (NHEADS == 32 ? 5 : 3));
    float p = (float)pos[s];
    // inv_freq = 10000^(-d/64) = exp(-d * ln(10000)/64)
    float inv = __expf(-(float)d * 0.14391156531310576f);
    float ang = p * inv;
    float sn = sinf(ang), cs = cosf(ang);
    size_t base = (size_t)s * (NHEADS * 128) + h * 128 + d;
    float x1 = b2f(T[base]), x2 = b2f(T[base + 64]);
    T[base]      = f2b(x1 * cs - x2 * sn);
    T[base + 64] = f2b(x2 * cs + x1 * sn);
}

// ---------------- GEMM: C[M][N] = A[M][K](bf16) * Bt[N][K](bf16) ----------------
// 128x128 tile, BK=32, 4 waves (2x2 of 64x64), mfma 16x16x32 bf16
template <bool BF16OUT>
__global__ __launch_bounds__(256) void gemm_bt(const u16* __restrict__ A,
                                               const u16* __restrict__ Bt,
                                               void* __restrict__ Cout,
                                               int N, int K) {
    __shared__ u16 Asm[128 * 32];
    __shared__ u16 Bsm[128 * 32];
    int tid = threadIdx.x;
    int wave = tid >> 6, lane = tid & 63;
    int l15 = lane & 15, l4 = lane >> 4;
    int m0 = blockIdx.y * 128, n0 = blockIdx.x * 128;
    int wm = wave >> 1, wn = wave & 1;
    f32x4 acc[4][4] = {};
    for (int k0 = 0; k0 < K; k0 += 32) {
        __syncthreads();
#pragma unroll
        for (int it = 0; it < 2; ++it) {
            int ch = wave * 128 + it * 64 + lane;
            int row = ch >> 2, cc = ch & 3;
            gload16(A  + (size_t)(m0 + row) * K + k0 + cc * 8,
                    Asm + (size_t)(wave * 128 + it * 64) * 8);
            gload16(Bt + (size_t)(n0 + row) * K + k0 + cc * 8,
                    Bsm + (size_t)(wave * 128 + it * 64) * 8);
        }
        __syncthreads();
        bf16x8 af[4], bf[4];
#pragma unroll
        for (int i = 0; i < 4; ++i)
            af[i] = *(const bf16x8*)(Asm + (wm * 64 + i * 16 + l15) * 32 + l4 * 8);
#pragma unroll
        for (int j = 0; j < 4; ++j)
            bf[j] = *(const bf16x8*)(Bsm + (wn * 64 + j * 16 + l15) * 32 + l4 * 8);
#pragma unroll
        for (int i = 0; i < 4; ++i)
#pragma unroll
            for (int j = 0; j < 4; ++j)
                acc[i][j] = __builtin_amdgcn_mfma_f32_16x16x32_bf16(af[i], bf[j], acc[i][j], 0, 0, 0);
    }
#pragma unroll
    for (int i = 0; i < 4; ++i)
#pragma unroll
        for (int j = 0; j < 4; ++j) {
            int col  = n0 + wn * 64 + j * 16 + l15;
            int rowb = m0 + wm * 64 + i * 16 + l4 * 4;
#pragma unroll
            for (int r = 0; r < 4; ++r) {
                if (BF16OUT)
                    ((u16*)Cout)[(size_t)(rowb + r) * N + col] = f2b(acc[i][j][r]);
                else
                    ((float*)Cout)[(size_t)(rowb + r) * N + col] = acc[i][j][r];
            }
        }
}

// ---------------- Flash attention (GQA, causal) ----------------
// grid (qb=32, h=32), 256 thr = 4 waves x 16 q-rows. KV step 32.
__global__ __launch_bounds__(256) void attn(const u16* __restrict__ Q,
                                            const u16* __restrict__ K,
                                            const u16* __restrict__ Vt,
                                            u16* __restrict__ O) {
    __shared__ u16 Ksm[32 * 128];  // [kv][d], chunk-swizzled
    __shared__ u16 Vsm[128 * 32];  // [d][kv], chunk-swizzled
    __shared__ u16 Psm[4][16 * 32];
    int h = blockIdx.y, hk = h >> 2;
    int qb = blockIdx.x;
    int tid = threadIdx.x, wave = tid >> 6, lane = tid & 63;
    int l15 = lane & 15, l4 = lane >> 4;
    int qr = qb * 64 + wave * 16;

    bf16x8 qf[4];
    const u16* qrow = Q + (size_t)(qr + l15) * 4096 + h * 128;
#pragma unroll
    for (int c = 0; c < 4; ++c) qf[c] = *(const bf16x8*)(qrow + c * 32 + l4 * 8);

    float mrow[4], lsum[4];
#pragma unroll
    for (int r = 0; r < 4; ++r) { mrow[r] = -1e30f; lsum[r] = 0.f; }
    f32x4 o[8] = {};
    const float scale = 0.08838834764831845f;  // 1/sqrt(128)
    int nkb = 2 * qb + 2;

    for (int kb = 0; kb < nkb; ++kb) {
        __syncthreads();
#pragma unroll
        for (int it = 0; it < 2; ++it) {
            int ch = wave * 128 + it * 64 + lane;
            {   // K tile: 32 rows x 128 d = 16 chunks/row; swizzle low3 of chunk by row
                int row = ch >> 4, cc = ch & 15;
                int csrc = (cc & 8) | ((cc ^ row) & 7);
                gload16(K + (size_t)(kb * 32 + row) * 1024 + hk * 128 + csrc * 8,
                        Ksm + (size_t)(wave * 128 + it * 64) * 8);
            }
            {   // V tile: 128 rows(d) x 32 kv = 4 chunks/row; swizzle 2 bits by row
                int row = ch >> 2, cc = ch & 3;
                int csrc = (cc ^ row) & 3;
                gload16(Vt + (size_t)hk * (128 * 2048) + (size_t)row * 2048 + kb * 32 + csrc * 8,
                        Vsm + (size_t)(wave * 128 + it * 64) * 8);
            }
        }
        __syncthreads();

        // S = Q K^T
        f32x4 sc[2] = {};
#pragma unroll
        for (int f = 0; f < 2; ++f) {
            int kv = f * 16 + l15;
#pragma unroll
            for (int c = 0; c < 4; ++c) {
                int cd = c * 4 + l4;
                int cpos = (cd & 8) | ((cd ^ kv) & 7);
                bf16x8 kf = *(const bf16x8*)(Ksm + kv * 128 + cpos * 8);
                sc[f] = __builtin_amdgcn_mfma_f32_16x16x32_bf16(qf[c], kf, sc[f], 0, 0, 0);
            }
        }
        // scale + causal mask + row max
        float sv[2][4];
        float bm[4] = {-1e30f, -1e30f, -1e30f, -1e30f};
#pragma unroll
        for (int f = 0; f < 2; ++f) {
            int col = kb * 32 + f * 16 + l15;
#pragma unroll
            for (int r = 0; r < 4; ++r) {
                int rowq = qr + l4 * 4 + r;
                float s = sc[f][r] * scale;
                if (col > rowq) s = -1e30f;
                sv[f][r] = s;
                bm[r] = fmaxf(bm[r], s);
            }
        }
#pragma unroll
        for (int msk = 1; msk < 16; msk <<= 1)
#pragma unroll
            for (int r = 0; r < 4; ++r) bm[r] = fmaxf(bm[r], __shfl_xor(bm[r], msk));

        float alpha[4], rs[4];
#pragma unroll
        for (int r = 0; r < 4; ++r) {
            float mn = fmaxf(mrow[r], bm[r]);
            alpha[r] = __expf(mrow[r] - mn);
            mrow[r] = mn;
            rs[r] = 0.f;
        }
        // P = exp(S - m), store to LDS (swizzled), accumulate row sums
#pragma unroll
        for (int f = 0; f < 2; ++f) {
#pragma unroll
            for (int r = 0; r < 4; ++r) {
                float p = __expf(sv[f][r] - mrow[r]);
                rs[r] += p;
                int prow = l4 * 4 + r;
                int col = f * 16 + l15;
                int cpos = (col >> 3) ^ (prow & 3);
                Psm[wave][prow * 32 + cpos * 8 + (col & 7)] = f2b(p);
            }
        }
#pragma unroll
        for (int msk = 1; msk < 16; msk <<= 1)
#pragma unroll
            for (int r = 0; r < 4; ++r) rs[r] += __shfl_xor(rs[r], msk);
#pragma unroll
        for (int r = 0; r < 4; ++r) lsum[r] = lsum[r] * alpha[r] + rs[r];
#pragma unroll
        for (int n = 0; n < 8; ++n)
#pragma unroll
            for (int r = 0; r < 4; ++r) o[n][r] *= alpha[r];

        // O += P V
        bf16x8 pf = *(const bf16x8*)(&Psm[wave][l15 * 32 + (l4 ^ (l15 & 3)) * 8]);
#pragma unroll
        for (int n = 0; n < 8; ++n) {
            int rowd = n * 16 + l15;
            int cpos = (l4 ^ rowd) & 3;
            bf16x8 vf = *(const bf16x8*)(Vsm + rowd * 32 + cpos * 8);
            o[n] = __builtin_amdgcn_mfma_f32_16x16x32_bf16(pf, vf, o[n], 0, 0, 0);
        }
    }
    // epilogue: O = acc / l
#pragma unroll
    for (int n = 0; n < 8; ++n)
#pragma unroll
        for (int r = 0; r < 4; ++r) {
            int rowq = qr + l4 * 4 + r;
            O[(size_t)rowq * 4096 + h * 128 + n * 16 + l15] = f2b(o[n][r] / lsum[r]);
        }
}

// ---------------- launch ----------------
extern "C" void kernel_launch(void* const* d_in, const int* in_sizes, int n_in,
                              void* d_out, int out_size, void* d_ws, size_t ws_size,
                              hipStream_t stream) {
    const int*   pos = (const int*)d_in[0];
    const float* X   = (const float*)d_in[1];
    const float* Wq  = (const float*)d_in[2];
    const float* Wk  = (const float*)d_in[3];
    const float* Wv  = (const float*)d_in[4];
    const float* Wo  = (const float*)d_in[5];
    float* out = (float*)d_out;

    char* w = (char*)d_ws;
    u16* Xb  = (u16*)(w + 0);
    u16* Wqt = (u16*)(w + 16777216);
    u16* Wkt = (u16*)(w + 50331648);
    u16* Wvt = (u16*)(w + 58720256);
    u16* Wot = (u16*)(w + 67108864);
    u16* Qb  = (u16*)(w + 100663296);
    u16* Kb  = (u16*)(w + 117440512);
    u16* Vb  = (u16*)(w + 121634816);
    u16* Vtb = (u16*)(w + 125829120);
    u16* Ob  = (u16*)(w + 130023424);

    // conversions
    cvt_x<<<4096, 256, 0, stream>>>(X, Xb, S * D / 8);
    tconv<<<dim3(64, 64), 256, 0, stream>>>(Wq, Wqt, 4096, 4096);
    tconv<<<dim3(16, 64), 256, 0, stream>>>(Wk, Wkt, 4096, 1024);
    tconv<<<dim3(16, 64), 256, 0, stream>>>(Wv, Wvt, 4096, 1024);
    tconv<<<dim3(64, 64), 256, 0, stream>>>(Wo, Wot, 4096, 4096);

    // projections
    gemm_bt<true><<<dim3(32, 16), 256, 0, stream>>>(Xb, Wqt, Qb, 4096, 4096);
    gemm_bt<true><<<dim3(8, 16), 256, 0, stream>>>(Xb, Wkt, Kb, 1024, 4096);
    gemm_bt<true><<<dim3(8, 16), 256, 0, stream>>>(Xb, Wvt, Vb, 1024, 4096);

    // rope
    rope_k<32><<<16384, 256, 0, stream>>>(Qb, pos);
    rope_k<8><<<4096, 256, 0, stream>>>(Kb, pos);

    // V transpose
    vtrans<<<dim3(32, 2, 8), 256, 0, stream>>>(Vb, Vtb);

    // attention
    attn<<<dim3(32, 32), 256, 0, stream>>>(Qb, Kb, Vtb, Ob);

    // output projection (f32 out)
    gemm_bt<false><<<dim3(32, 16), 256, 0, stream>>>(Ob, Wot, out, 4096, 4096);
}

// Round 4
// 521.915 us; speedup vs baseline: 1.3108x; 1.3108x over previous
//
#include <hip/hip_runtime.h>

typedef unsigned short u16;
typedef short bf16x8 __attribute__((ext_vector_type(8)));
typedef float f32x4 __attribute__((ext_vector_type(4)));

#define GLB __attribute__((address_space(1)))
#define LDSAS __attribute__((address_space(3)))

constexpr int S = 2048, D = 4096, NH = 32, NHK = 8, DHD = 128;
constexpr int NQKV = 6144;  // 4096 q + 1024 k + 1024 v

__device__ __forceinline__ u16 f2b(float f) {
    union { float f; unsigned u; } v; v.f = f;
    return (u16)((v.u + 0x7fffu + ((v.u >> 16) & 1u)) >> 16);
}
__device__ __forceinline__ float b2f(u16 b) {
    union { unsigned u; float f; } v; v.u = ((unsigned)b) << 16;
    return v.f;
}
__device__ __forceinline__ void gload16(const void* g, void* l) {
    __builtin_amdgcn_global_load_lds((const GLB unsigned int*)g,
                                     (LDSAS unsigned int*)l, 16, 0, 0);
}
#if __has_builtin(__builtin_amdgcn_exp2f)
__device__ __forceinline__ float exp2fast(float x) { return __builtin_amdgcn_exp2f(x); }
#else
__device__ __forceinline__ float exp2fast(float x) { return __expf(0.6931471805599453f * x); }
#endif

// Accurate sin/cos for large args: reduce to revolutions in [0,1), then v_sin/v_cos
// (v_sin_f32 takes REVOLUTIONS; raw large-angle input is out of range).
__device__ __forceinline__ void sincos_big(float ang, float* sn, float* cs) {
#if __has_builtin(__builtin_amdgcn_sinf) && __has_builtin(__builtin_amdgcn_cosf)
    float rev = ang * 0.15915494309189535f;  // 1/(2*pi)
    rev = rev - floorf(rev);                 // [0,1) — in range for v_sin/v_cos
    *sn = __builtin_amdgcn_sinf(rev);
    *cs = __builtin_amdgcn_cosf(rev);
#else
    *sn = sinf(ang);
    *cs = cosf(ang);
#endif
}

// ---------------- f32 -> bf16 elementwise (8/thread) ----------------
__global__ __launch_bounds__(256) void cvt_x(const float* __restrict__ in,
                                             u16* __restrict__ out, int n8) {
    int i = blockIdx.x * 256 + threadIdx.x;
    if (i >= n8) return;
    const float4* p = (const float4*)in + (size_t)i * 2;
    float4 a = p[0], b = p[1];
    uint4 o;
    o.x = f2b(a.x) | ((unsigned)f2b(a.y) << 16);
    o.y = f2b(a.z) | ((unsigned)f2b(a.w) << 16);
    o.z = f2b(b.x) | ((unsigned)f2b(b.y) << 16);
    o.w = f2b(b.z) | ((unsigned)f2b(b.w) << 16);
    *(uint4*)(out + (size_t)i * 8) = o;
}

// ---------------- f32 [R][C] -> bf16 [C][R] ----------------
__global__ __launch_bounds__(256) void tconv(const float* __restrict__ in,
                                             u16* __restrict__ out, int R, int C) {
    __shared__ float t[64][65];
    int r0 = blockIdx.y * 64, c0 = blockIdx.x * 64;
    int tx = threadIdx.x & 63, ty = threadIdx.x >> 6;
#pragma unroll
    for (int i = 0; i < 64; i += 4)
        t[ty + i][tx] = in[(size_t)(r0 + ty + i) * C + c0 + tx];
    __syncthreads();
#pragma unroll
    for (int i = 0; i < 64; i += 4)
        out[(size_t)(c0 + ty + i) * R + r0 + tx] = f2b(t[tx][ty + i]);
}

// ---------------- bf16 V (QKV cols 5120..6143) -> Vt [hk][d][s] ----------------
__global__ __launch_bounds__(256) void vtrans(const u16* __restrict__ QKV,
                                              u16* __restrict__ Vt) {
    __shared__ u16 t[64][65];
    int hk = blockIdx.z;
    int s0 = blockIdx.x * 64, d0 = blockIdx.y * 64;
    int tx = threadIdx.x & 63, ty = threadIdx.x >> 6;
#pragma unroll
    for (int i = 0; i < 64; i += 4)
        t[ty + i][tx] = QKV[(size_t)(s0 + ty + i) * NQKV + 5120 + hk * 128 + d0 + tx];
    __syncthreads();
#pragma unroll
    for (int i = 0; i < 64; i += 4)
        Vt[(size_t)hk * (128 * 2048) + (size_t)(d0 + ty + i) * 2048 + s0 + tx] = t[tx][ty + i];
}

// ---------------- RoPE in place, bf16, stride NQKV; scale folded in ----------------
template <int NHEADS>
__global__ __launch_bounds__(256) void rope2(u16* __restrict__ T,
                                             const int* __restrict__ pos, float scale) {
    int idx = blockIdx.x * 256 + threadIdx.x;
    int d = idx & 63;
    int h = (idx >> 6) & (NHEADS - 1);
    int s = idx >> (6 + (NHEADS == 32 ? 5 : 3));
    float p = (float)pos[s];
    float inv = __expf(-(float)d * 0.14391156531310576f);  // 10000^(-d/64)
    float ang = p * inv;
    float sn, cs;
    sincos_big(ang, &sn, &cs);
    size_t base = (size_t)s * NQKV + h * 128 + d;
    float x1 = b2f(T[base]), x2 = b2f(T[base + 64]);
    T[base]      = f2b((x1 * cs - x2 * sn) * scale);
    T[base + 64] = f2b((x2 * cs + x1 * sn) * scale);
}

// ---------------- GEMM: C[M][N] = A[M][K](bf16) * Bt[N][K](bf16) ----------------
template <bool BF16OUT>
__global__ __launch_bounds__(256) void gemm_bt(const u16* __restrict__ A,
                                               const u16* __restrict__ Bt,
                                               void* __restrict__ Cout,
                                               int N, int K) {
    __shared__ u16 Asm[128 * 32];
    __shared__ u16 Bsm[128 * 32];
    int tid = threadIdx.x;
    int wave = tid >> 6, lane = tid & 63;
    int l15 = lane & 15, l4 = lane >> 4;
    int m0 = blockIdx.y * 128, n0 = blockIdx.x * 128;
    int wm = wave >> 1, wn = wave & 1;
    f32x4 acc[4][4] = {};
    for (int k0 = 0; k0 < K; k0 += 32) {
        __syncthreads();
#pragma unroll
        for (int it = 0; it < 2; ++it) {
            int ch = wave * 128 + it * 64 + lane;
            int row = ch >> 2, cc = ch & 3;
            gload16(A  + (size_t)(m0 + row) * K + k0 + cc * 8,
                    Asm + (size_t)(wave * 128 + it * 64) * 8);
            gload16(Bt + (size_t)(n0 + row) * K + k0 + cc * 8,
                    Bsm + (size_t)(wave * 128 + it * 64) * 8);
        }
        __syncthreads();
        bf16x8 af[4], bf[4];
#pragma unroll
        for (int i = 0; i < 4; ++i)
            af[i] = *(const bf16x8*)(Asm + (wm * 64 + i * 16 + l15) * 32 + l4 * 8);
#pragma unroll
        for (int j = 0; j < 4; ++j)
            bf[j] = *(const bf16x8*)(Bsm + (wn * 64 + j * 16 + l15) * 32 + l4 * 8);
#pragma unroll
        for (int i = 0; i < 4; ++i)
#pragma unroll
            for (int j = 0; j < 4; ++j)
                acc[i][j] = __builtin_amdgcn_mfma_f32_16x16x32_bf16(af[i], bf[j], acc[i][j], 0, 0, 0);
    }
#pragma unroll
    for (int i = 0; i < 4; ++i)
#pragma unroll
        for (int j = 0; j < 4; ++j) {
            int col  = n0 + wn * 64 + j * 16 + l15;
            int rowb = m0 + wm * 64 + i * 16 + l4 * 4;
#pragma unroll
            for (int r = 0; r < 4; ++r) {
                if (BF16OUT)
                    ((u16*)Cout)[(size_t)(rowb + r) * N + col] = f2b(acc[i][j][r]);
                else
                    ((float*)Cout)[(size_t)(rowb + r) * N + col] = acc[i][j][r];
            }
        }
}

// ---------------- Flash attention v2: prefetch dbuf, KVBLK=64, 32 rows/wave ----------------
// grid (16 qb-blocks reversed, 32 heads), 256 thr = 4 waves x 32 q-rows.
__global__ __launch_bounds__(256) void attn2(const u16* __restrict__ QKV,
                                             const u16* __restrict__ Vt,
                                             u16* __restrict__ O) {
    __shared__ u16 Ksm[2][64 * 128];  // [kv][d-chunk swz]
    __shared__ u16 Vsm[2][128 * 64];  // [d][kv-chunk swz]
    __shared__ u16 Psm[4][16 * 64];   // per-wave P tile, swz
    const int h = blockIdx.y, hk = h >> 2;
    const int qb = (int)gridDim.x - 1 - (int)blockIdx.x;  // heavy blocks dispatch first
    const int tid = threadIdx.x, wave = tid >> 6, lane = tid & 63;
    const int l15 = lane & 15, l4 = lane >> 4;
    const int qr0 = qb * 128 + wave * 32;
    const u16* Qp = QKV + h * 128;
    const u16* Kp = QKV + 4096 + hk * 128;
    const u16* Vp = Vt + (size_t)hk * (128 * 2048);

    bf16x8 qf[2][4];
#pragma unroll
    for (int t = 0; t < 2; ++t) {
        const u16* qrow = Qp + (size_t)(qr0 + t * 16 + l15) * NQKV;
#pragma unroll
        for (int c = 0; c < 4; ++c)
            qf[t][c] = *(const bf16x8*)(qrow + c * 32 + l4 * 8);
    }

    float mrow[2][4], lsum[2][4];
#pragma unroll
    for (int t = 0; t < 2; ++t)
#pragma unroll
        for (int r = 0; r < 4; ++r) { mrow[t][r] = -1e30f; lsum[t][r] = 0.f; }
    f32x4 o[2][8] = {};

    const int nkb = 2 * qb + 2;

    auto stage = [&](int kb, int b) {
#pragma unroll
        for (int it = 0; it < 4; ++it) {
            int L = it * 256 + tid;
            int krow = L >> 4, kslot = L & 15;
            int kcs = (kslot & 8) | ((kslot ^ krow) & 7);
            gload16(Kp + (size_t)(kb * 64 + krow) * NQKV + kcs * 8, &Ksm[b][L * 8]);
            int vrow = L >> 3, vslot = L & 7;
            int vcs = (vslot ^ vrow) & 7;
            gload16(Vp + (size_t)vrow * 2048 + kb * 64 + vcs * 8, &Vsm[b][L * 8]);
        }
    };

    stage(0, 0);
    for (int kb = 0; kb < nkb; ++kb) {
        const int cur = kb & 1;
        if (kb + 1 < nkb) {
            stage(kb + 1, cur ^ 1);
            asm volatile("s_waitcnt vmcnt(8)" ::: "memory");  // prev tile's 8 loads done
        } else {
            asm volatile("s_waitcnt vmcnt(0)" ::: "memory");
        }
        __builtin_amdgcn_s_barrier();

        if (kb * 64 <= qr0 + 31) {  // wave has unmasked work this step
            const u16* Kb_ = Ksm[cur];
            const u16* Vb_ = Vsm[cur];
            const bool diag = (kb * 64 + 63 > qr0);
            // ---- S = Q K^T (log2 domain: scale*log2e folded into Q) ----
            f32x4 sc[2][4] = {};
#pragma unroll
            for (int f = 0; f < 4; ++f) {
                const int kv = f * 16 + l15;
                bf16x8 kf[4];
#pragma unroll
                for (int c = 0; c < 4; ++c) {
                    int cd = c * 4 + l4;
                    int cpos = (cd & 8) | ((cd ^ kv) & 7);
                    kf[c] = *(const bf16x8*)(Kb_ + kv * 128 + cpos * 8);
                }
#pragma unroll
                for (int t = 0; t < 2; ++t)
#pragma unroll
                    for (int c = 0; c < 4; ++c)
                        sc[t][f] = __builtin_amdgcn_mfma_f32_16x16x32_bf16(qf[t][c], kf[c], sc[t][f], 0, 0, 0);
            }
#pragma unroll
            for (int t = 0; t < 2; ++t) {
                if (diag) {
#pragma unroll
                    for (int f = 0; f < 4; ++f) {
                        int col = kb * 64 + f * 16 + l15;
#pragma unroll
                        for (int r = 0; r < 4; ++r) {
                            int row = qr0 + t * 16 + l4 * 4 + r;
                            if (col > row) sc[t][f][r] = -1e30f;
                        }
                    }
                }
                float bm[4];
#pragma unroll
                for (int r = 0; r < 4; ++r)
                    bm[r] = fmaxf(fmaxf(sc[t][0][r], sc[t][1][r]), fmaxf(sc[t][2][r], sc[t][3][r]));
#pragma unroll
                for (int msk = 1; msk < 16; msk <<= 1)
#pragma unroll
                    for (int r = 0; r < 4; ++r) bm[r] = fmaxf(bm[r], __shfl_xor(bm[r], msk));

                bool need = false;
#pragma unroll
                for (int r = 0; r < 4; ++r) need = need || (bm[r] > mrow[t][r] + 8.0f);
                if (__any((int)need)) {  // T13 defer-rescale (per-ROW alpha — component-indexed!)
                    float al[4];
#pragma unroll
                    for (int r = 0; r < 4; ++r) {
                        float mn = fmaxf(mrow[t][r], bm[r]);
                        al[r] = exp2fast(mrow[t][r] - mn);
                        mrow[t][r] = mn;
                        lsum[t][r] *= al[r];
                    }
#pragma unroll
                    for (int n = 0; n < 8; ++n)
#pragma unroll
                        for (int r = 0; r < 4; ++r) o[t][n][r] *= al[r];
                }
                float rs[4] = {0.f, 0.f, 0.f, 0.f};
#pragma unroll
                for (int f = 0; f < 4; ++f) {
#pragma unroll
                    for (int r = 0; r < 4; ++r) {
                        float p = exp2fast(sc[t][f][r] - mrow[t][r]);
                        rs[r] += p;
                        int q = l4 * 4 + r;
                        int kvc = f * 2 + (l15 >> 3);
                        int slot = (kvc ^ q) & 7;
                        Psm[wave][q * 64 + slot * 8 + (l15 & 7)] = f2b(p);
                    }
                }
#pragma unroll
                for (int msk = 1; msk < 16; msk <<= 1)
#pragma unroll
                    for (int r = 0; r < 4; ++r) rs[r] += __shfl_xor(rs[r], msk);
#pragma unroll
                for (int r = 0; r < 4; ++r) lsum[t][r] += rs[r];

                asm volatile("s_waitcnt lgkmcnt(0)" ::: "memory");
                bf16x8 pf[2];
#pragma unroll
                for (int c = 0; c < 2; ++c) {
                    int chc = c * 4 + l4;
                    int slot = (chc ^ l15) & 7;
                    pf[c] = *(const bf16x8*)(&Psm[wave][l15 * 64 + slot * 8]);
                }
#pragma unroll
                for (int n = 0; n < 8; ++n) {
                    int d = n * 16 + l15;
                    bf16x8 vf[2];
#pragma unroll
                    for (int c = 0; c < 2; ++c) {
                        int ch = c * 4 + l4;
                        int slot = (ch ^ d) & 7;
                        vf[c] = *(const bf16x8*)(Vb_ + d * 64 + slot * 8);
                    }
#pragma unroll
                    for (int c = 0; c < 2; ++c)
                        o[t][n] = __builtin_amdgcn_mfma_f32_16x16x32_bf16(pf[c], vf[c], o[t][n], 0, 0, 0);
                }
            }  // t
        }  // active
        asm volatile("s_waitcnt lgkmcnt(0)" ::: "memory");
        __builtin_amdgcn_s_barrier();
    }

    // epilogue: O = acc / l
#pragma unroll
    for (int t = 0; t < 2; ++t) {
        float inv[4];
#pragma unroll
        for (int r = 0; r < 4; ++r) inv[r] = 1.0f / lsum[t][r];
#pragma unroll
        for (int n = 0; n < 8; ++n)
#pragma unroll
            for (int r = 0; r < 4; ++r) {
                int row = qr0 + t * 16 + l4 * 4 + r;
                O[(size_t)row * 4096 + h * 128 + n * 16 + l15] = f2b(o[t][n][r] * inv[r]);
            }
    }
}

// ---------------- launch ----------------
extern "C" void kernel_launch(void* const* d_in, const int* in_sizes, int n_in,
                              void* d_out, int out_size, void* d_ws, size_t ws_size,
                              hipStream_t stream) {
    const int*   pos = (const int*)d_in[0];
    const float* X   = (const float*)d_in[1];
    const float* Wq  = (const float*)d_in[2];
    const float* Wk  = (const float*)d_in[3];
    const float* Wv  = (const float*)d_in[4];
    const float* Wo  = (const float*)d_in[5];
    float* out = (float*)d_out;

    char* w = (char*)d_ws;
    u16* Xb    = (u16*)(w + 0);          //  16.78 MB
    u16* Wqkvt = (u16*)(w + 16777216);   //  50.33 MB [6144][4096]
    u16* Wot   = (u16*)(w + 67108864);   //  33.55 MB
    u16* QKV   = (u16*)(w + 100663296);  //  25.17 MB [2048][6144]
    u16* Vtb   = (u16*)(w + 125829120);  //   4.19 MB [8][128][2048]
    u16* Ob    = (u16*)(w + 130023424);  //  16.78 MB

    const float SC2 = 0.08838834764831845f * 1.4426950408889634f;  // 1/sqrt(128) * log2(e)

    // conversions / weight transposes (QKV weights packed into one [6144][4096])
    cvt_x<<<4096, 256, 0, stream>>>(X, Xb, S * D / 8);
    tconv<<<dim3(64, 64), 256, 0, stream>>>(Wq, Wqkvt, 4096, 4096);
    tconv<<<dim3(16, 64), 256, 0, stream>>>(Wk, Wqkvt + (size_t)4096 * 4096, 4096, 1024);
    tconv<<<dim3(16, 64), 256, 0, stream>>>(Wv, Wqkvt + (size_t)5120 * 4096, 4096, 1024);
    tconv<<<dim3(64, 64), 256, 0, stream>>>(Wo, Wot, 4096, 4096);

    // fused QKV projection: [2048][6144]
    gemm_bt<true><<<dim3(48, 16), 256, 0, stream>>>(Xb, Wqkvt, QKV, NQKV, 4096);

    // rope (scale*log2e folded into Q)
    rope2<32><<<16384, 256, 0, stream>>>(QKV, pos, SC2);
    rope2<8><<<4096, 256, 0, stream>>>(QKV + 4096, pos, 1.0f);

    // V transpose
    vtrans<<<dim3(32, 2, 8), 256, 0, stream>>>(QKV, Vtb);

    // attention
    attn2<<<dim3(16, 32), 256, 0, stream>>>(QKV, Vtb, Ob);

    // output projection (f32 out)
    gemm_bt<false><<<dim3(32, 16), 256, 0, stream>>>(Ob, Wot, out, 4096, 4096);
}

// Round 5
// 405.692 us; speedup vs baseline: 1.6863x; 1.2865x over previous
//
#include <hip/hip_runtime.h>

typedef unsigned short u16;
typedef short bf16x8 __attribute__((ext_vector_type(8)));
typedef float f32x4 __attribute__((ext_vector_type(4)));

#define GLB __attribute__((address_space(1)))
#define LDSAS __attribute__((address_space(3)))

constexpr int S = 2048, D = 4096, NH = 32, NHK = 8, DHD = 128;
constexpr int NQKV = 6144;  // 4096 q + 1024 k + 1024 v

__device__ __forceinline__ u16 f2b(float f) {
    union { float f; unsigned u; } v; v.f = f;
    return (u16)((v.u + 0x7fffu + ((v.u >> 16) & 1u)) >> 16);
}
__device__ __forceinline__ float b2f(u16 b) {
    union { unsigned u; float f; } v; v.u = ((unsigned)b) << 16;
    return v.f;
}
__device__ __forceinline__ void gload16(const void* g, void* l) {
    __builtin_amdgcn_global_load_lds((const GLB unsigned int*)g,
                                     (LDSAS unsigned int*)l, 16, 0, 0);
}
#if __has_builtin(__builtin_amdgcn_exp2f)
__device__ __forceinline__ float exp2fast(float x) { return __builtin_amdgcn_exp2f(x); }
#else
__device__ __forceinline__ float exp2fast(float x) { return __expf(0.6931471805599453f * x); }
#endif

// Accurate sin/cos for large args: reduce to revolutions in [0,1), then v_sin/v_cos.
__device__ __forceinline__ void sincos_big(float ang, float* sn, float* cs) {
#if __has_builtin(__builtin_amdgcn_sinf) && __has_builtin(__builtin_amdgcn_cosf)
    float rev = ang * 0.15915494309189535f;  // 1/(2*pi)
    rev = rev - floorf(rev);                 // [0,1)
    *sn = __builtin_amdgcn_sinf(rev);
    *cs = __builtin_amdgcn_cosf(rev);
#else
    *sn = sinf(ang);
    *cs = cosf(ang);
#endif
}

// ---------------- f32 -> bf16 elementwise (8/thread) ----------------
__global__ __launch_bounds__(256) void cvt_x(const float* __restrict__ in,
                                             u16* __restrict__ out, int n8) {
    int i = blockIdx.x * 256 + threadIdx.x;
    if (i >= n8) return;
    const float4* p = (const float4*)in + (size_t)i * 2;
    float4 a = p[0], b = p[1];
    uint4 o;
    o.x = f2b(a.x) | ((unsigned)f2b(a.y) << 16);
    o.y = f2b(a.z) | ((unsigned)f2b(a.w) << 16);
    o.z = f2b(b.x) | ((unsigned)f2b(b.y) << 16);
    o.w = f2b(b.z) | ((unsigned)f2b(b.w) << 16);
    *(uint4*)(out + (size_t)i * 8) = o;
}

// ---------------- f32 [R][C] -> bf16 [C][R] ----------------
__global__ __launch_bounds__(256) void tconv(const float* __restrict__ in,
                                             u16* __restrict__ out, int R, int C) {
    __shared__ float t[64][65];
    int r0 = blockIdx.y * 64, c0 = blockIdx.x * 64;
    int tx = threadIdx.x & 63, ty = threadIdx.x >> 6;
#pragma unroll
    for (int i = 0; i < 64; i += 4)
        t[ty + i][tx] = in[(size_t)(r0 + ty + i) * C + c0 + tx];
    __syncthreads();
#pragma unroll
    for (int i = 0; i < 64; i += 4)
        out[(size_t)(c0 + ty + i) * R + r0 + tx] = f2b(t[tx][ty + i]);
}

// ---------------- bf16 V (QKV cols 5120..6143) -> Vt [hk][d][s] ----------------
__global__ __launch_bounds__(256) void vtrans(const u16* __restrict__ QKV,
                                              u16* __restrict__ Vt) {
    __shared__ u16 t[64][65];
    int hk = blockIdx.z;
    int s0 = blockIdx.x * 64, d0 = blockIdx.y * 64;
    int tx = threadIdx.x & 63, ty = threadIdx.x >> 6;
#pragma unroll
    for (int i = 0; i < 64; i += 4)
        t[ty + i][tx] = QKV[(size_t)(s0 + ty + i) * NQKV + 5120 + hk * 128 + d0 + tx];
    __syncthreads();
#pragma unroll
    for (int i = 0; i < 64; i += 4)
        Vt[(size_t)hk * (128 * 2048) + (size_t)(d0 + ty + i) * 2048 + s0 + tx] = t[tx][ty + i];
}

// ---------------- RoPE in place, bf16, stride NQKV; scale folded in ----------------
template <int NHEADS>
__global__ __launch_bounds__(256) void rope2(u16* __restrict__ T,
                                             const int* __restrict__ pos, float scale) {
    int idx = blockIdx.x * 256 + threadIdx.x;
    int d = idx & 63;
    int h = (idx >> 6) & (NHEADS - 1);
    int s = idx >> (6 + (NHEADS == 32 ? 5 : 3));
    float p = (float)pos[s];
    float inv = __expf(-(float)d * 0.14391156531310576f);  // 10000^(-d/64)
    float ang = p * inv;
    float sn, cs;
    sincos_big(ang, &sn, &cs);
    size_t base = (size_t)s * NQKV + h * 128 + d;
    float x1 = b2f(T[base]), x2 = b2f(T[base + 64]);
    T[base]      = f2b((x1 * cs - x2 * sn) * scale);
    T[base + 64] = f2b((x2 * cs + x1 * sn) * scale);
}

// ---------------- GEMM: C[M][N] = A[M][K](bf16) * Bt[N][K](bf16) ----------------
template <bool BF16OUT>
__global__ __launch_bounds__(256) void gemm_bt(const u16* __restrict__ A,
                                               const u16* __restrict__ Bt,
                                               void* __restrict__ Cout,
                                               int N, int K) {
    __shared__ u16 Asm[128 * 32];
    __shared__ u16 Bsm[128 * 32];
    int tid = threadIdx.x;
    int wave = tid >> 6, lane = tid & 63;
    int l15 = lane & 15, l4 = lane >> 4;
    int m0 = blockIdx.y * 128, n0 = blockIdx.x * 128;
    int wm = wave >> 1, wn = wave & 1;
    f32x4 acc[4][4] = {};
    for (int k0 = 0; k0 < K; k0 += 32) {
        __syncthreads();
#pragma unroll
        for (int it = 0; it < 2; ++it) {
            int ch = wave * 128 + it * 64 + lane;
            int row = ch >> 2, cc = ch & 3;
            gload16(A  + (size_t)(m0 + row) * K + k0 + cc * 8,
                    Asm + (size_t)(wave * 128 + it * 64) * 8);
            gload16(Bt + (size_t)(n0 + row) * K + k0 + cc * 8,
                    Bsm + (size_t)(wave * 128 + it * 64) * 8);
        }
        __syncthreads();
        bf16x8 af[4], bf[4];
#pragma unroll
        for (int i = 0; i < 4; ++i)
            af[i] = *(const bf16x8*)(Asm + (wm * 64 + i * 16 + l15) * 32 + l4 * 8);
#pragma unroll
        for (int j = 0; j < 4; ++j)
            bf[j] = *(const bf16x8*)(Bsm + (wn * 64 + j * 16 + l15) * 32 + l4 * 8);
#pragma unroll
        for (int i = 0; i < 4; ++i)
#pragma unroll
            for (int j = 0; j < 4; ++j)
                acc[i][j] = __builtin_amdgcn_mfma_f32_16x16x32_bf16(af[i], bf[j], acc[i][j], 0, 0, 0);
    }
#pragma unroll
    for (int i = 0; i < 4; ++i)
#pragma unroll
        for (int j = 0; j < 4; ++j) {
            int col  = n0 + wn * 64 + j * 16 + l15;
            int rowb = m0 + wm * 64 + i * 16 + l4 * 4;
#pragma unroll
            for (int r = 0; r < 4; ++r) {
                if (BF16OUT)
                    ((u16*)Cout)[(size_t)(rowb + r) * N + col] = f2b(acc[i][j][r]);
                else
                    ((float*)Cout)[(size_t)(rowb + r) * N + col] = acc[i][j][r];
            }
        }
}

// ---------------- Flash attention v3: balanced tile pairs ----------------
// 1024 causal tiles (32 qt x 32 h), QBLK=64 (4 waves x 16 rows), KVBLK=64.
// Block b handles tiles (31-p, p) of head h => every block = 33-34 steps.
// grid 512 1-D; bijective XCD chunk swizzle keeps one hk-group per XCD L2.
__global__ __launch_bounds__(256) void attn3(const u16* __restrict__ QKV,
                                             const u16* __restrict__ Vt,
                                             u16* __restrict__ O) {
    __shared__ u16 Ksm[2][64 * 128];  // [kv][d-chunk swz]
    __shared__ u16 Vsm[2][128 * 64];  // [d][kv-chunk swz]
    __shared__ u16 Psm[4][16 * 64];   // per-wave P tile, swz
    const int orig = blockIdx.x;
    const int swz = (orig & 7) * 64 + (orig >> 3);   // 512 = 8*64, bijective
    const int h = swz >> 4, p = swz & 15;
    const int hk = h >> 2;
    const int tid = threadIdx.x, wave = tid >> 6, lane = tid & 63;
    const int l15 = lane & 15, l4 = lane >> 4;
    const u16* Qp = QKV + h * 128;
    const u16* Kp = QKV + 4096 + hk * 128;
    const u16* Vp = Vt + (size_t)hk * (128 * 2048);

    auto stage = [&](int kb, int b) {
#pragma unroll
        for (int it = 0; it < 4; ++it) {
            int L = it * 256 + tid;
            int krow = L >> 4, kslot = L & 15;
            int kcs = (kslot & 8) | ((kslot ^ krow) & 7);
            gload16(Kp + (size_t)(kb * 64 + krow) * NQKV + kcs * 8, &Ksm[b][L * 8]);
            int vrow = L >> 3, vslot = L & 7;
            int vcs = (vslot ^ vrow) & 7;
            gload16(Vp + (size_t)vrow * 2048 + kb * 64 + vcs * 8, &Vsm[b][L * 8]);
        }
    };

#pragma unroll 1
    for (int pass = 0; pass < 2; ++pass) {
        const int qt = pass ? p : 31 - p;
        const int qr0 = qt * 64 + wave * 16;
        const int nkb = qt + 1;

        bf16x8 qf[4];
        {
            const u16* qrow = Qp + (size_t)(qr0 + l15) * NQKV;
#pragma unroll
            for (int c = 0; c < 4; ++c)
                qf[c] = *(const bf16x8*)(qrow + c * 32 + l4 * 8);
        }
        float mrow[4], lsum[4];
#pragma unroll
        for (int r = 0; r < 4; ++r) { mrow[r] = -1e30f; lsum[r] = 0.f; }
        f32x4 o[8] = {};

        stage(0, 0);
#pragma unroll 1
        for (int kb = 0; kb < nkb; ++kb) {
            const int cur = kb & 1;
            if (kb + 1 < nkb) {
                stage(kb + 1, cur ^ 1);
                asm volatile("s_waitcnt vmcnt(8)" ::: "memory");
            } else {
                asm volatile("s_waitcnt vmcnt(0)" ::: "memory");
            }
            __builtin_amdgcn_s_barrier();

            if (kb * 64 <= qr0 + 15) {  // wave has unmasked work
                const u16* Kb_ = Ksm[cur];
                const u16* Vb_ = Vsm[cur];
                const bool diag = (kb * 64 + 63 > qr0);
                // ---- S = Q K^T (log2 domain) ----
                f32x4 sc[4] = {};
#pragma unroll
                for (int f = 0; f < 4; ++f) {
                    const int kv = f * 16 + l15;
#pragma unroll
                    for (int c = 0; c < 4; ++c) {
                        int cd = c * 4 + l4;
                        int cpos = (cd & 8) | ((cd ^ kv) & 7);
                        bf16x8 kf = *(const bf16x8*)(Kb_ + kv * 128 + cpos * 8);
                        sc[f] = __builtin_amdgcn_mfma_f32_16x16x32_bf16(qf[c], kf, sc[f], 0, 0, 0);
                    }
                }
                if (diag) {
#pragma unroll
                    for (int f = 0; f < 4; ++f) {
                        int col = kb * 64 + f * 16 + l15;
#pragma unroll
                        for (int r = 0; r < 4; ++r) {
                            int row = qr0 + l4 * 4 + r;
                            if (col > row) sc[f][r] = -1e30f;
                        }
                    }
                }
                float bm[4];
#pragma unroll
                for (int r = 0; r < 4; ++r)
                    bm[r] = fmaxf(fmaxf(sc[0][r], sc[1][r]), fmaxf(sc[2][r], sc[3][r]));
#pragma unroll
                for (int msk = 1; msk < 16; msk <<= 1)
#pragma unroll
                    for (int r = 0; r < 4; ++r) bm[r] = fmaxf(bm[r], __shfl_xor(bm[r], msk));

                bool need = false;
#pragma unroll
                for (int r = 0; r < 4; ++r) need = need || (bm[r] > mrow[r] + 8.0f);
                if (__any((int)need)) {  // T13 defer-rescale, per-row alpha
                    float al[4];
#pragma unroll
                    for (int r = 0; r < 4; ++r) {
                        float mn = fmaxf(mrow[r], bm[r]);
                        al[r] = exp2fast(mrow[r] - mn);
                        mrow[r] = mn;
                        lsum[r] *= al[r];
                    }
#pragma unroll
                    for (int n = 0; n < 8; ++n)
#pragma unroll
                        for (int r = 0; r < 4; ++r) o[n][r] *= al[r];
                }
                float rs[4] = {0.f, 0.f, 0.f, 0.f};
#pragma unroll
                for (int f = 0; f < 4; ++f) {
#pragma unroll
                    for (int r = 0; r < 4; ++r) {
                        float pw = exp2fast(sc[f][r] - mrow[r]);
                        rs[r] += pw;
                        int q = l4 * 4 + r;
                        int kvc = f * 2 + (l15 >> 3);
                        int slot = (kvc ^ q) & 7;
                        Psm[wave][q * 64 + slot * 8 + (l15 & 7)] = f2b(pw);
                    }
                }
#pragma unroll
                for (int msk = 1; msk < 16; msk <<= 1)
#pragma unroll
                    for (int r = 0; r < 4; ++r) rs[r] += __shfl_xor(rs[r], msk);
#pragma unroll
                for (int r = 0; r < 4; ++r) lsum[r] += rs[r];

                asm volatile("s_waitcnt lgkmcnt(0)" ::: "memory");
                bf16x8 pf[2];
#pragma unroll
                for (int c = 0; c < 2; ++c) {
                    int chc = c * 4 + l4;
                    int slot = (chc ^ l15) & 7;
                    pf[c] = *(const bf16x8*)(&Psm[wave][l15 * 64 + slot * 8]);
                }
#pragma unroll
                for (int n = 0; n < 8; ++n) {
                    int d = n * 16 + l15;
                    bf16x8 vf[2];
#pragma unroll
                    for (int c = 0; c < 2; ++c) {
                        int ch = c * 4 + l4;
                        int slot = (ch ^ d) & 7;
                        vf[c] = *(const bf16x8*)(Vb_ + d * 64 + slot * 8);
                    }
#pragma unroll
                    for (int c = 0; c < 2; ++c)
                        o[n] = __builtin_amdgcn_mfma_f32_16x16x32_bf16(pf[c], vf[c], o[n], 0, 0, 0);
                }
            }  // active
            asm volatile("s_waitcnt lgkmcnt(0)" ::: "memory");
            __builtin_amdgcn_s_barrier();
        }

        // epilogue: O = acc / l
        float inv[4];
#pragma unroll
        for (int r = 0; r < 4; ++r) inv[r] = 1.0f / lsum[r];
#pragma unroll
        for (int n = 0; n < 8; ++n)
#pragma unroll
            for (int r = 0; r < 4; ++r) {
                int row = qr0 + l4 * 4 + r;
                O[(size_t)row * 4096 + h * 128 + n * 16 + l15] = f2b(o[n][r] * inv[r]);
            }
    }  // pass
}

// ---------------- launch ----------------
extern "C" void kernel_launch(void* const* d_in, const int* in_sizes, int n_in,
                              void* d_out, int out_size, void* d_ws, size_t ws_size,
                              hipStream_t stream) {
    const int*   pos = (const int*)d_in[0];
    const float* X   = (const float*)d_in[1];
    const float* Wq  = (const float*)d_in[2];
    const float* Wk  = (const float*)d_in[3];
    const float* Wv  = (const float*)d_in[4];
    const float* Wo  = (const float*)d_in[5];
    float* out = (float*)d_out;

    char* w = (char*)d_ws;
    u16* Xb    = (u16*)(w + 0);          //  16.78 MB
    u16* Wqkvt = (u16*)(w + 16777216);   //  50.33 MB [6144][4096]
    u16* Wot   = (u16*)(w + 67108864);   //  33.55 MB
    u16* QKV   = (u16*)(w + 100663296);  //  25.17 MB [2048][6144]
    u16* Vtb   = (u16*)(w + 125829120);  //   4.19 MB [8][128][2048]
    u16* Ob    = (u16*)(w + 130023424);  //  16.78 MB

    const float SC2 = 0.08838834764831845f * 1.4426950408889634f;  // 1/sqrt(128) * log2(e)

    // conversions / weight transposes (QKV weights packed into one [6144][4096])
    cvt_x<<<4096, 256, 0, stream>>>(X, Xb, S * D / 8);
    tconv<<<dim3(64, 64), 256, 0, stream>>>(Wq, Wqkvt, 4096, 4096);
    tconv<<<dim3(16, 64), 256, 0, stream>>>(Wk, Wqkvt + (size_t)4096 * 4096, 4096, 1024);
    tconv<<<dim3(16, 64), 256, 0, stream>>>(Wv, Wqkvt + (size_t)5120 * 4096, 4096, 1024);
    tconv<<<dim3(64, 64), 256, 0, stream>>>(Wo, Wot, 4096, 4096);

    // fused QKV projection: [2048][6144]
    gemm_bt<true><<<dim3(48, 16), 256, 0, stream>>>(Xb, Wqkvt, QKV, NQKV, 4096);

    // rope (scale*log2e folded into Q)
    rope2<32><<<16384, 256, 0, stream>>>(QKV, pos, SC2);
    rope2<8><<<4096, 256, 0, stream>>>(QKV + 4096, pos, 1.0f);

    // V transpose
    vtrans<<<dim3(32, 2, 8), 256, 0, stream>>>(QKV, Vtb);

    // attention (balanced pairs)
    attn3<<<512, 256, 0, stream>>>(QKV, Vtb, Ob);

    // output projection (f32 out)
    gemm_bt<false><<<dim3(32, 16), 256, 0, stream>>>(Ob, Wot, out, 4096, 4096);
}